// Round 13
// baseline (133.735 us; speedup 1.0000x reference)
//
#include <hip/hip_runtime.h>

#define NN   8192
#define DD   128
#define KM1  7
#define TPB  256
#define NBLK 512      // 16-col weight blocks per row

#define O0_END   57344
#define O1_END   7397376
#define O2_END   14737408
#define O3_END   22077440
#define TOTAL    23126016
#define NKEY     57344

typedef __attribute__((ext_vector_type(8))) short bf16x8;
typedef __attribute__((ext_vector_type(4))) float f32x4;

__device__ __forceinline__ unsigned mix32(unsigned h) {
  h ^= h >> 16; h *= 0x85ebca6bu; h ^= h >> 13; h *= 0xc2b2ae35u; h ^= h >> 16;
  return h;
}

// Weight of pair given dot (bf16 inputs). Same formula in both passes.
__device__ __forceinline__ float wfun(float dot, int col, int rowblk) {
  float d2m = fmaxf(fmaf(-2.f, dot, 2.f), 0.25f);      // clamped dist^2
  bool vb = ((col >> 3) != rowblk) && (d2m < 1.96f);   // block mask + dist<1.4
  float lgd = __log2f(d2m);
  float om  = fmaf(-0.25f, d2m, 1.f);
  float lgo = __log2f(om);
  float lgw = fmaf(-62.5f, lgo, fmaf(-63.f, lgd, -63.f));  // log2 w
  float w   = __builtin_amdgcn_exp2f(lgw);             // w in [8e-20, 5e20]
  return vb ? w : 0.f;
}

__device__ __forceinline__ float wave_incl_scan(float v, int lane) {
#pragma unroll
  for (int off = 1; off < 64; off <<= 1) {
    float t = __shfl_up(v, off);
    if (lane >= off) v += t;
  }
  return v;
}

// fp32 -> bf16 (RNE), 4 elems/thread
__global__ __launch_bounds__(256) void to_bf16(const float4* __restrict__ x4,
                                               ushort4* __restrict__ xb4) {
  const int i = blockIdx.x * 256 + threadIdx.x;
  float4 v = x4[i];
  ushort4 o;
  unsigned u;
  u = __float_as_uint(v.x); o.x = (unsigned short)((u + 0x7FFFu + ((u >> 16) & 1u)) >> 16);
  u = __float_as_uint(v.y); o.y = (unsigned short)((u + 0x7FFFu + ((u >> 16) & 1u)) >> 16);
  u = __float_as_uint(v.z); o.z = (unsigned short)((u + 0x7FFFu + ((u >> 16) & 1u)) >> 16);
  u = __float_as_uint(v.w); o.w = (unsigned short)((u + 0x7FFFu + ((u >> 16) & 1u)) >> 16);
  xb4[i] = o;
}

// Pass A (swapped operands, 64 rows/wave): wave = 64 rows x 256 cols (8 tiles).
// grid = 32 row-groups x 32 col-chunks = 1024 blocks -> 4 waves/SIMD ceiling.
__global__ __launch_bounds__(TPB, 4) void pass_a(const unsigned short* __restrict__ xb,
                                                 float* __restrict__ bs) {
  const int tid  = threadIdx.x;
  const int lane = tid & 63;
  const int wid  = tid >> 6;
  const int l15  = lane & 15;
  const int g    = lane >> 4;
  const int i0   = ((int)(blockIdx.x >> 5)) * 256 + wid * 64;  // wave's 64 rows
  const int oc   = (int)(blockIdx.x & 31);
  const int c0   = oc * 256;
  const int koff = g * 8;

  // row fragments (B operand, n = row): 4 groups of 16 rows, loaded once
  bf16x8 rw[4][4];
#pragma unroll
  for (int rg = 0; rg < 4; ++rg) {
    const unsigned short* rp = xb + (size_t)(i0 + rg * 16 + l15) * DD + koff;
#pragma unroll
    for (int kk = 0; kk < 4; ++kk)
      rw[rg][kk] = *reinterpret_cast<const bf16x8*>(rp + kk * 32);
  }

#pragma unroll 2
  for (int t = 0; t < 8; ++t) {           // 32-col tiles = 2 x 16-col blocks
    const int ct = c0 + t * 32;
    // col fragments (A operand, m = col): lane l15 -> col ct+mf*16+l15
    bf16x8 cf[2][4];
#pragma unroll
    for (int mf = 0; mf < 2; ++mf) {
      const unsigned short* cp = xb + (size_t)(ct + mf * 16 + l15) * DD + koff;
#pragma unroll
      for (int kk = 0; kk < 4; ++kk)
        cf[mf][kk] = *reinterpret_cast<const bf16x8*>(cp + kk * 32);
    }

    f32x4 acc[2][4];
#pragma unroll
    for (int mf = 0; mf < 2; ++mf)
#pragma unroll
      for (int rg = 0; rg < 4; ++rg) acc[mf][rg] = (f32x4){0.f, 0.f, 0.f, 0.f};

#pragma unroll
    for (int mf = 0; mf < 2; ++mf)
#pragma unroll
      for (int rg = 0; rg < 4; ++rg)
#pragma unroll
        for (int kk = 0; kk < 4; ++kk)
          acc[mf][rg] = __builtin_amdgcn_mfma_f32_16x16x32_bf16(cf[mf][kk], rw[rg][kk],
                                                                acc[mf][rg], 0, 0, 0);

    // D layout [m89]: n = l15 -> our ROW (in group rg); m = g*4+reg -> our COL
#pragma unroll
    for (int mf = 0; mf < 2; ++mf)
#pragma unroll
      for (int rg = 0; rg < 4; ++rg) {
        const int myrow = i0 + rg * 16 + l15;
        const int rowblk = myrow >> 3;
        float s = 0.f;
#pragma unroll
        for (int r = 0; r < 4; ++r) {
          const int col = ct + mf * 16 + g * 4 + r;
          s += wfun(acc[mf][rg][r], col, rowblk);
        }
        s += __shfl_xor(s, 16);
        s += __shfl_xor(s, 32);            // sum over g: 16-col block sum
        if (g == 0) bs[(size_t)myrow * NBLK + (ct >> 4) + mf] = s;
      }
  }
}

// Pass B: one wave per draw. Two-level inverse-CDF: 512 block sums -> 16-col
// block -> fp32 recompute of the 16 weights (4 lanes/col x 32 dims).
__global__ __launch_bounds__(TPB) void pass_b(const unsigned short* __restrict__ xb,
                                              const float* __restrict__ bs,
                                              unsigned* __restrict__ nidx) {
  const int lane = threadIdx.x & 63;
  const int wid  = threadIdx.x >> 6;
  const int draw = (int)blockIdx.x * 4 + wid;   // 57344 draws
  const int row  = draw / KM1;

  // ---- stage 1: scan the row's 512 block sums (8 per lane)
  const float* bsr = bs + (size_t)row * NBLK;
  float4 v0 = *reinterpret_cast<const float4*>(bsr + lane * 8);
  float4 v1 = *reinterpret_cast<const float4*>(bsr + lane * 8 + 4);
  float s8 = ((v0.x + v0.y) + (v0.z + v0.w)) + ((v1.x + v1.y) + (v1.z + v1.w));
  float pre = wave_incl_scan(s8, lane);
  float W = __shfl(pre, 63);

  unsigned h = mix32((unsigned)draw * 2654435761u + 0x12345u);
  float u = ((float)(h >> 9) + 0.5f) * (1.0f / 8388608.0f);   // (0,1)

  if (!(W > 0.f)) {  // degenerate row -> uniform over all n
    if (lane == 0) nidx[draw] = mix32((unsigned)draw * 0x68bc21ebu + 77u) & (NN - 1);
    return;
  }
  float target = u * W;

  unsigned long long ball = __ballot(pre >= target);
  int Lc = ball ? ((int)__ffsll(ball) - 1) : 63;
  float exL = __shfl(pre - s8, Lc);
  float a0 = __shfl(v0.x, Lc), a1 = __shfl(v0.y, Lc), a2 = __shfl(v0.z, Lc),
        a3 = __shfl(v0.w, Lc), a4 = __shfl(v1.x, Lc), a5 = __shfl(v1.y, Lc),
        a6 = __shfl(v1.z, Lc), a7 = __shfl(v1.w, Lc);
  // uniform scalar selection among the 8 (static indexing only)
  int k = -1; float res = 0.f, bsb = 0.f, c = exL;
#define PICK(j, aj) { float cn = c + (aj); if (k < 0 && cn >= target) { k = j; res = target - c; bsb = (aj); } c = cn; }
  PICK(0, a0) PICK(1, a1) PICK(2, a2) PICK(3, a3)
  PICK(4, a4) PICK(5, a5) PICK(6, a6) PICK(7, a7)
#undef PICK
#define LASTP(j, aj) { if (k < 0 && (aj) > 0.f) { k = j; res = (aj); bsb = (aj); } }
  LASTP(7, a7) LASTP(6, a6) LASTP(5, a5) LASTP(4, a4)
  LASTP(3, a3) LASTP(2, a2) LASTP(1, a1) LASTP(0, a0)
#undef LASTP
  if (k < 0) {  // pathological: chosen lane empty -> uniform fallback
    if (lane == 0) nidx[draw] = mix32((unsigned)draw * 0x68bc21ebu + 77u) & (NN - 1);
    return;
  }
  const int blk = Lc * 8 + k;
  const int cb  = blk * 16;

  // ---- stage 2: recompute the 16 weights in fp32 (4 lanes/col x 32 dims)
  const int c_local = lane >> 2;
  const int part    = lane & 3;
  const int col     = cb + c_local;
  const unsigned short* cp = xb + (size_t)col * DD + part * 32;
  const unsigned short* ap = xb + (size_t)row * DD + part * 32;
  float dot = 0.f;
#pragma unroll
  for (int vv = 0; vv < 4; ++vv) {
    bf16x8 cv = *reinterpret_cast<const bf16x8*>(cp + vv * 8);
    bf16x8 av = *reinterpret_cast<const bf16x8*>(ap + vv * 8);
#pragma unroll
    for (int j = 0; j < 8; ++j) {
      float cf = __uint_as_float(((unsigned)(unsigned short)cv[j]) << 16);
      float af = __uint_as_float(((unsigned)(unsigned short)av[j]) << 16);
      dot = fmaf(cf, af, dot);
    }
  }
  dot += __shfl_xor(dot, 1);
  dot += __shfl_xor(dot, 2);
  float w = wfun(dot, col, row >> 3);
  float v = (part == 0) ? w : 0.f;
  float pre2 = wave_incl_scan(v, lane);
  float SW = __shfl(pre2, 63);
  unsigned result;
  if (SW > 0.f) {
    float t2 = (res / bsb) * SW;                 // renormalized residual
    unsigned long long m = __ballot((v > 0.f) && (pre2 >= t2));
    if (m) result = (unsigned)(cb + (((int)__ffsll(m) - 1) >> 2));
    else {
      unsigned long long m2 = __ballot(v > 0.f); // rounding overrun -> clamp
      result = (unsigned)(cb + ((63 - (int)__clzll(m2)) >> 2));
    }
  } else {
    result = mix32((unsigned)draw * 0x68bc21ebu + 77u) & (NN - 1);
  }
  if (lane == 0) nidx[draw] = result;
}

// All five output chunks, float4-vectorized.
__global__ __launch_bounds__(256) void write_outputs(const float* __restrict__ x,
                                                     const unsigned* __restrict__ nidx,
                                                     float4* __restrict__ out4) {
  const int qq = blockIdx.x * 256 + threadIdx.x;
  if (qq >= TOTAL / 4) return;
  const int e = qq * 4;
  float4 v;
  if (e < O0_END) {
    v.x = (float)((e    ) / KM1);
    v.y = (float)((e + 1) / KM1);
    v.z = (float)((e + 2) / KM1);
    v.w = (float)((e + 3) / KM1);                        // a_idx
  } else if (e < O1_END) {
    int t = e - O0_END; int sidx = t >> 7; int d = t & 127;
    v = *reinterpret_cast<const float4*>(x + (size_t)(sidx / KM1) * DD + d);   // x[a_idx]
  } else if (e < O2_END) {
    int t = e - O1_END; int sidx = t >> 7; int d = t & 127;
    int i = sidx / KM1; int j = sidx - i * KM1; int m = i & 7;
    int p = (i >> 3) * 8 + j + (j >= m ? 1 : 0);         // block members, skip self
    v = *reinterpret_cast<const float4*>(x + (size_t)p * DD + d);              // x[p_idx]
  } else if (e < O3_END) {
    int t = e - O2_END; int sidx = t >> 7; int d = t & 127;
    int nix = (int)nidx[sidx];
    v = *reinterpret_cast<const float4*>(x + (size_t)nix * DD + d);            // x[n_idx]
  } else {
    v = *reinterpret_cast<const float4*>(x + (e - O3_END));                    // x
  }
  out4[qq] = v;
}

extern "C" void kernel_launch(void* const* d_in, const int* in_sizes, int n_in,
                              void* d_out, int out_size, void* d_ws, size_t ws_size,
                              hipStream_t stream) {
  const float* x = (const float*)d_in[0];
  float* out = (float*)d_out;

  float* bs = (float*)d_ws;                                           // 8192*512 f32 = 16MB
  unsigned* nidx = (unsigned*)((char*)d_ws + (size_t)NN * NBLK * 4);  // 57344 u32
  unsigned short* xb = (unsigned short*)((char*)nidx + NKEY * 4);     // 2MB bf16

  hipLaunchKernelGGL(to_bf16, dim3(NN * DD / 4 / 256), dim3(256), 0, stream,
                     (const float4*)x, (ushort4*)xb);
  hipLaunchKernelGGL(pass_a, dim3(1024), dim3(TPB), 0, stream, xb, bs);
  hipLaunchKernelGGL(pass_b, dim3(NKEY / 4), dim3(TPB), 0, stream, xb, bs, nidx);
  hipLaunchKernelGGL(write_outputs, dim3(TOTAL / 4 / 256), dim3(256), 0, stream,
                     x, nidx, (float4*)out);
}

// Round 14
// 128.671 us; speedup vs baseline: 1.0394x; 1.0394x over previous
//
#include <hip/hip_runtime.h>

#define NN   8192
#define DD   128
#define KM1  7
#define TPB  256
#define NBLK 512      // 16-col weight blocks per row

#define O0_END   57344
#define O1_END   7397376
#define O2_END   14737408
#define O3_END   22077440
#define TOTAL    23126016
#define NKEY     57344

typedef __attribute__((ext_vector_type(8))) short bf16x8;
typedef __attribute__((ext_vector_type(4))) float f32x4;

__device__ __forceinline__ unsigned mix32(unsigned h) {
  h ^= h >> 16; h *= 0x85ebca6bu; h ^= h >> 13; h *= 0xc2b2ae35u; h ^= h >> 16;
  return h;
}

// Weight of pair given dot (bf16 inputs). Same formula in both passes.
__device__ __forceinline__ float wfun(float dot, int col, int rowblk) {
  float d2m = fmaxf(fmaf(-2.f, dot, 2.f), 0.25f);      // clamped dist^2
  bool vb = ((col >> 3) != rowblk) && (d2m < 1.96f);   // block mask + dist<1.4
  float lgd = __log2f(d2m);
  float om  = fmaf(-0.25f, d2m, 1.f);
  float lgo = __log2f(om);
  float lgw = fmaf(-62.5f, lgo, fmaf(-63.f, lgd, -63.f));  // log2 w
  float w   = __builtin_amdgcn_exp2f(lgw);             // w in [8e-20, 5e20]
  return vb ? w : 0.f;
}

__device__ __forceinline__ float wave_incl_scan(float v, int lane) {
#pragma unroll
  for (int off = 1; off < 64; off <<= 1) {
    float t = __shfl_up(v, off);
    if (lane >= off) v += t;
  }
  return v;
}

// fp32 -> bf16 (RNE), 4 elems/thread
__global__ __launch_bounds__(256) void to_bf16(const float4* __restrict__ x4,
                                               ushort4* __restrict__ xb4) {
  const int i = blockIdx.x * 256 + threadIdx.x;
  float4 v = x4[i];
  ushort4 o;
  unsigned u;
  u = __float_as_uint(v.x); o.x = (unsigned short)((u + 0x7FFFu + ((u >> 16) & 1u)) >> 16);
  u = __float_as_uint(v.y); o.y = (unsigned short)((u + 0x7FFFu + ((u >> 16) & 1u)) >> 16);
  u = __float_as_uint(v.z); o.z = (unsigned short)((u + 0x7FFFu + ((u >> 16) & 1u)) >> 16);
  u = __float_as_uint(v.w); o.w = (unsigned short)((u + 0x7FFFu + ((u >> 16) & 1u)) >> 16);
  xb4[i] = o;
}

// Pass A (swapped operands, 64 rows/wave): wave = 64 rows x 256 cols (8 tiles).
// Identical codegen to R12 (launch_bounds 2, unroll 1, VGPR 68, no spills);
// only the grid doubled: 32 row-groups x 32 col-chunks = 1024 blocks.
__global__ __launch_bounds__(TPB, 2) void pass_a(const unsigned short* __restrict__ xb,
                                                 float* __restrict__ bs) {
  const int tid  = threadIdx.x;
  const int lane = tid & 63;
  const int wid  = tid >> 6;
  const int l15  = lane & 15;
  const int g    = lane >> 4;
  const int i0   = ((int)(blockIdx.x >> 5)) * 256 + wid * 64;  // wave's 64 rows
  const int oc   = (int)(blockIdx.x & 31);
  const int c0   = oc * 256;
  const int koff = g * 8;

  // row fragments (B operand, n = row): 4 groups of 16 rows, loaded once
  bf16x8 rw[4][4];
#pragma unroll
  for (int rg = 0; rg < 4; ++rg) {
    const unsigned short* rp = xb + (size_t)(i0 + rg * 16 + l15) * DD + koff;
#pragma unroll
    for (int kk = 0; kk < 4; ++kk)
      rw[rg][kk] = *reinterpret_cast<const bf16x8*>(rp + kk * 32);
  }

#pragma unroll 1
  for (int t = 0; t < 8; ++t) {           // 32-col tiles = 2 x 16-col blocks
    const int ct = c0 + t * 32;
    // col fragments (A operand, m = col): lane l15 -> col ct+mf*16+l15
    bf16x8 cf[2][4];
#pragma unroll
    for (int mf = 0; mf < 2; ++mf) {
      const unsigned short* cp = xb + (size_t)(ct + mf * 16 + l15) * DD + koff;
#pragma unroll
      for (int kk = 0; kk < 4; ++kk)
        cf[mf][kk] = *reinterpret_cast<const bf16x8*>(cp + kk * 32);
    }

    f32x4 acc[2][4];
#pragma unroll
    for (int mf = 0; mf < 2; ++mf)
#pragma unroll
      for (int rg = 0; rg < 4; ++rg) acc[mf][rg] = (f32x4){0.f, 0.f, 0.f, 0.f};

#pragma unroll
    for (int mf = 0; mf < 2; ++mf)
#pragma unroll
      for (int rg = 0; rg < 4; ++rg)
#pragma unroll
        for (int kk = 0; kk < 4; ++kk)
          acc[mf][rg] = __builtin_amdgcn_mfma_f32_16x16x32_bf16(cf[mf][kk], rw[rg][kk],
                                                                acc[mf][rg], 0, 0, 0);

    // D layout [m89]: n = l15 -> our ROW (in group rg); m = g*4+reg -> our COL
#pragma unroll
    for (int mf = 0; mf < 2; ++mf)
#pragma unroll
      for (int rg = 0; rg < 4; ++rg) {
        const int myrow = i0 + rg * 16 + l15;
        const int rowblk = myrow >> 3;
        float s = 0.f;
#pragma unroll
        for (int r = 0; r < 4; ++r) {
          const int col = ct + mf * 16 + g * 4 + r;
          s += wfun(acc[mf][rg][r], col, rowblk);
        }
        s += __shfl_xor(s, 16);
        s += __shfl_xor(s, 32);            // sum over g: 16-col block sum
        if (g == 0) bs[(size_t)myrow * NBLK + (ct >> 4) + mf] = s;
      }
  }
}

// Pass B: one wave per draw. Two-level inverse-CDF: 512 block sums -> 16-col
// block -> fp32 recompute of the 16 weights (4 lanes/col x 32 dims).
__global__ __launch_bounds__(TPB) void pass_b(const unsigned short* __restrict__ xb,
                                              const float* __restrict__ bs,
                                              unsigned* __restrict__ nidx) {
  const int lane = threadIdx.x & 63;
  const int wid  = threadIdx.x >> 6;
  const int draw = (int)blockIdx.x * 4 + wid;   // 57344 draws
  const int row  = draw / KM1;

  // ---- stage 1: scan the row's 512 block sums (8 per lane)
  const float* bsr = bs + (size_t)row * NBLK;
  float4 v0 = *reinterpret_cast<const float4*>(bsr + lane * 8);
  float4 v1 = *reinterpret_cast<const float4*>(bsr + lane * 8 + 4);
  float s8 = ((v0.x + v0.y) + (v0.z + v0.w)) + ((v1.x + v1.y) + (v1.z + v1.w));
  float pre = wave_incl_scan(s8, lane);
  float W = __shfl(pre, 63);

  unsigned h = mix32((unsigned)draw * 2654435761u + 0x12345u);
  float u = ((float)(h >> 9) + 0.5f) * (1.0f / 8388608.0f);   // (0,1)

  if (!(W > 0.f)) {  // degenerate row -> uniform over all n
    if (lane == 0) nidx[draw] = mix32((unsigned)draw * 0x68bc21ebu + 77u) & (NN - 1);
    return;
  }
  float target = u * W;

  unsigned long long ball = __ballot(pre >= target);
  int Lc = ball ? ((int)__ffsll(ball) - 1) : 63;
  float exL = __shfl(pre - s8, Lc);
  float a0 = __shfl(v0.x, Lc), a1 = __shfl(v0.y, Lc), a2 = __shfl(v0.z, Lc),
        a3 = __shfl(v0.w, Lc), a4 = __shfl(v1.x, Lc), a5 = __shfl(v1.y, Lc),
        a6 = __shfl(v1.z, Lc), a7 = __shfl(v1.w, Lc);
  // uniform scalar selection among the 8 (static indexing only)
  int k = -1; float res = 0.f, bsb = 0.f, c = exL;
#define PICK(j, aj) { float cn = c + (aj); if (k < 0 && cn >= target) { k = j; res = target - c; bsb = (aj); } c = cn; }
  PICK(0, a0) PICK(1, a1) PICK(2, a2) PICK(3, a3)
  PICK(4, a4) PICK(5, a5) PICK(6, a6) PICK(7, a7)
#undef PICK
#define LASTP(j, aj) { if (k < 0 && (aj) > 0.f) { k = j; res = (aj); bsb = (aj); } }
  LASTP(7, a7) LASTP(6, a6) LASTP(5, a5) LASTP(4, a4)
  LASTP(3, a3) LASTP(2, a2) LASTP(1, a1) LASTP(0, a0)
#undef LASTP
  if (k < 0) {  // pathological: chosen lane empty -> uniform fallback
    if (lane == 0) nidx[draw] = mix32((unsigned)draw * 0x68bc21ebu + 77u) & (NN - 1);
    return;
  }
  const int blk = Lc * 8 + k;
  const int cb  = blk * 16;

  // ---- stage 2: recompute the 16 weights in fp32 (4 lanes/col x 32 dims)
  const int c_local = lane >> 2;
  const int part    = lane & 3;
  const int col     = cb + c_local;
  const unsigned short* cp = xb + (size_t)col * DD + part * 32;
  const unsigned short* ap = xb + (size_t)row * DD + part * 32;
  float dot = 0.f;
#pragma unroll
  for (int vv = 0; vv < 4; ++vv) {
    bf16x8 cv = *reinterpret_cast<const bf16x8*>(cp + vv * 8);
    bf16x8 av = *reinterpret_cast<const bf16x8*>(ap + vv * 8);
#pragma unroll
    for (int j = 0; j < 8; ++j) {
      float cf = __uint_as_float(((unsigned)(unsigned short)cv[j]) << 16);
      float af = __uint_as_float(((unsigned)(unsigned short)av[j]) << 16);
      dot = fmaf(cf, af, dot);
    }
  }
  dot += __shfl_xor(dot, 1);
  dot += __shfl_xor(dot, 2);
  float w = wfun(dot, col, row >> 3);
  float v = (part == 0) ? w : 0.f;
  float pre2 = wave_incl_scan(v, lane);
  float SW = __shfl(pre2, 63);
  unsigned result;
  if (SW > 0.f) {
    float t2 = (res / bsb) * SW;                 // renormalized residual
    unsigned long long m = __ballot((v > 0.f) && (pre2 >= t2));
    if (m) result = (unsigned)(cb + (((int)__ffsll(m) - 1) >> 2));
    else {
      unsigned long long m2 = __ballot(v > 0.f); // rounding overrun -> clamp
      result = (unsigned)(cb + ((63 - (int)__clzll(m2)) >> 2));
    }
  } else {
    result = mix32((unsigned)draw * 0x68bc21ebu + 77u) & (NN - 1);
  }
  if (lane == 0) nidx[draw] = result;
}

// All five output chunks, float4-vectorized.
__global__ __launch_bounds__(256) void write_outputs(const float* __restrict__ x,
                                                     const unsigned* __restrict__ nidx,
                                                     float4* __restrict__ out4) {
  const int qq = blockIdx.x * 256 + threadIdx.x;
  if (qq >= TOTAL / 4) return;
  const int e = qq * 4;
  float4 v;
  if (e < O0_END) {
    v.x = (float)((e    ) / KM1);
    v.y = (float)((e + 1) / KM1);
    v.z = (float)((e + 2) / KM1);
    v.w = (float)((e + 3) / KM1);                        // a_idx
  } else if (e < O1_END) {
    int t = e - O0_END; int sidx = t >> 7; int d = t & 127;
    v = *reinterpret_cast<const float4*>(x + (size_t)(sidx / KM1) * DD + d);   // x[a_idx]
  } else if (e < O2_END) {
    int t = e - O1_END; int sidx = t >> 7; int d = t & 127;
    int i = sidx / KM1; int j = sidx - i * KM1; int m = i & 7;
    int p = (i >> 3) * 8 + j + (j >= m ? 1 : 0);         // block members, skip self
    v = *reinterpret_cast<const float4*>(x + (size_t)p * DD + d);              // x[p_idx]
  } else if (e < O3_END) {
    int t = e - O2_END; int sidx = t >> 7; int d = t & 127;
    int nix = (int)nidx[sidx];
    v = *reinterpret_cast<const float4*>(x + (size_t)nix * DD + d);            // x[n_idx]
  } else {
    v = *reinterpret_cast<const float4*>(x + (e - O3_END));                    // x
  }
  out4[qq] = v;
}

extern "C" void kernel_launch(void* const* d_in, const int* in_sizes, int n_in,
                              void* d_out, int out_size, void* d_ws, size_t ws_size,
                              hipStream_t stream) {
  const float* x = (const float*)d_in[0];
  float* out = (float*)d_out;

  float* bs = (float*)d_ws;                                           // 8192*512 f32 = 16MB
  unsigned* nidx = (unsigned*)((char*)d_ws + (size_t)NN * NBLK * 4);  // 57344 u32
  unsigned short* xb = (unsigned short*)((char*)nidx + NKEY * 4);     // 2MB bf16

  hipLaunchKernelGGL(to_bf16, dim3(NN * DD / 4 / 256), dim3(256), 0, stream,
                     (const float4*)x, (ushort4*)xb);
  hipLaunchKernelGGL(pass_a, dim3(1024), dim3(TPB), 0, stream, xb, bs);
  hipLaunchKernelGGL(pass_b, dim3(NKEY / 4), dim3(TPB), 0, stream, xb, bs, nidx);
  hipLaunchKernelGGL(write_outputs, dim3(TOTAL / 4 / 256), dim3(256), 0, stream,
                     x, nidx, (float4*)out);
}

// Round 15
// 116.678 us; speedup vs baseline: 1.1462x; 1.1028x over previous
//
#include <hip/hip_runtime.h>

#define NN   8192
#define DD   128
#define KM1  7
#define TPB  256
#define NBLK 512      // 16-col weight blocks per row

#define O0_END   57344
#define O1_END   7397376
#define O2_END   14737408
#define O3_END   22077440
#define TOTAL    23126016
#define NKEY     57344

typedef __attribute__((ext_vector_type(8))) short bf16x8;
typedef __attribute__((ext_vector_type(4))) float f32x4;

__device__ __forceinline__ unsigned mix32(unsigned h) {
  h ^= h >> 16; h *= 0x85ebca6bu; h ^= h >> 13; h *= 0xc2b2ae35u; h ^= h >> 16;
  return h;
}

// Weight of pair given dot (bf16 inputs). Same formula in both passes.
__device__ __forceinline__ float wfun(float dot, int col, int rowblk) {
  float d2m = fmaxf(fmaf(-2.f, dot, 2.f), 0.25f);      // clamped dist^2
  bool vb = ((col >> 3) != rowblk) && (d2m < 1.96f);   // block mask + dist<1.4
  float lgd = __log2f(d2m);
  float om  = fmaf(-0.25f, d2m, 1.f);
  float lgo = __log2f(om);
  float lgw = fmaf(-62.5f, lgo, fmaf(-63.f, lgd, -63.f));  // log2 w
  float w   = __builtin_amdgcn_exp2f(lgw);             // w in [8e-20, 5e20]
  return vb ? w : 0.f;
}

__device__ __forceinline__ float wave_incl_scan(float v, int lane) {
#pragma unroll
  for (int off = 1; off < 64; off <<= 1) {
    float t = __shfl_up(v, off);
    if (lane >= off) v += t;
  }
  return v;
}

// fp32 -> bf16 (RNE), 4 elems/thread
__global__ __launch_bounds__(256) void to_bf16(const float4* __restrict__ x4,
                                               ushort4* __restrict__ xb4) {
  const int i = blockIdx.x * 256 + threadIdx.x;
  float4 v = x4[i];
  ushort4 o;
  unsigned u;
  u = __float_as_uint(v.x); o.x = (unsigned short)((u + 0x7FFFu + ((u >> 16) & 1u)) >> 16);
  u = __float_as_uint(v.y); o.y = (unsigned short)((u + 0x7FFFu + ((u >> 16) & 1u)) >> 16);
  u = __float_as_uint(v.z); o.z = (unsigned short)((u + 0x7FFFu + ((u >> 16) & 1u)) >> 16);
  u = __float_as_uint(v.w); o.w = (unsigned short)((u + 0x7FFFu + ((u >> 16) & 1u)) >> 16);
  xb4[i] = o;
}

// Pass A (swapped operands, 64 rows/wave): wave = 64 rows x 512 cols (16 tiles).
// R12 grid/codegen config; bs accumulated per-lane (lane = row) and written as
// 4 coalesced float4 stores at the end (full-line writes, no RMW amplification).
__global__ __launch_bounds__(TPB, 2) void pass_a(const unsigned short* __restrict__ xb,
                                                 float* __restrict__ bs) {
  const int tid  = threadIdx.x;
  const int lane = tid & 63;
  const int wid  = tid >> 6;
  const int l15  = lane & 15;
  const int g    = lane >> 4;
  const int i0   = ((int)(blockIdx.x >> 4)) * 256 + wid * 64;  // wave's 64 rows
  const int oc   = (int)(blockIdx.x & 15);
  const int c0   = oc * 512;
  const int koff = g * 8;

  // row fragments (B operand, n = row): 4 groups of 16 rows, loaded once
  bf16x8 rw[4][4];
#pragma unroll
  for (int rg = 0; rg < 4; ++rg) {
    const unsigned short* rp = xb + (size_t)(i0 + rg * 16 + l15) * DD + koff;
#pragma unroll
    for (int kk = 0; kk < 4; ++kk)
      rw[rg][kk] = *reinterpret_cast<const bf16x8*>(rp + kk * 32);
  }

  float bsl[32];     // this lane's row (i0+lane): 32 block sums, static-indexed
#pragma unroll
  for (int j = 0; j < 32; ++j) bsl[j] = 0.f;

#pragma unroll 1
  for (int t = 0; t < 16; ++t) {          // 32-col tiles = 2 x 16-col blocks
    const int ct = c0 + t * 32;
    // col fragments (A operand, m = col): lane l15 -> col ct+mf*16+l15
    bf16x8 cf[2][4];
#pragma unroll
    for (int mf = 0; mf < 2; ++mf) {
      const unsigned short* cp = xb + (size_t)(ct + mf * 16 + l15) * DD + koff;
#pragma unroll
      for (int kk = 0; kk < 4; ++kk)
        cf[mf][kk] = *reinterpret_cast<const bf16x8*>(cp + kk * 32);
    }

    f32x4 acc[2][4];
#pragma unroll
    for (int mf = 0; mf < 2; ++mf)
#pragma unroll
      for (int rg = 0; rg < 4; ++rg) acc[mf][rg] = (f32x4){0.f, 0.f, 0.f, 0.f};

#pragma unroll
    for (int mf = 0; mf < 2; ++mf)
#pragma unroll
      for (int rg = 0; rg < 4; ++rg)
#pragma unroll
        for (int kk = 0; kk < 4; ++kk)
          acc[mf][rg] = __builtin_amdgcn_mfma_f32_16x16x32_bf16(cf[mf][kk], rw[rg][kk],
                                                                acc[mf][rg], 0, 0, 0);

    // D layout [m89]: n = l15 -> ROW (group rg); m = g*4+reg -> COL
#pragma unroll
    for (int mf = 0; mf < 2; ++mf) {
      float s[4];
#pragma unroll
      for (int rg = 0; rg < 4; ++rg) {
        const int rowblk = (i0 + rg * 16 + l15) >> 3;
        float sv = 0.f;
#pragma unroll
        for (int r = 0; r < 4; ++r) {
          const int col = ct + mf * 16 + g * 4 + r;
          sv += wfun(acc[mf][rg][r], col, rowblk);
        }
        sv += __shfl_xor(sv, 16);
        sv += __shfl_xor(sv, 32);          // sum over g -> 16-col block sum
        s[rg] = sv;
      }
      // keep the rg == g slice: lane now owns row i0+lane
      float v = (g == 0) ? s[0] : (g == 1) ? s[1] : (g == 2) ? s[2] : s[3];
      bsl[2 * t + mf] = v;
    }
  }

  // coalesced write: lane's row chunk = 32 consecutive floats (128 B)
  float* dst = bs + (size_t)(i0 + lane) * NBLK + oc * 32;
#pragma unroll
  for (int k4 = 0; k4 < 8; ++k4) {
    float4 o = {bsl[4 * k4], bsl[4 * k4 + 1], bsl[4 * k4 + 2], bsl[4 * k4 + 3]};
    *reinterpret_cast<float4*>(dst + 4 * k4) = o;
  }
}

// Pass B: one wave per draw. Two-level inverse-CDF: 512 block sums -> 16-col
// block -> fp32 recompute of the 16 weights (4 lanes/col x 32 dims).
__global__ __launch_bounds__(TPB) void pass_b(const unsigned short* __restrict__ xb,
                                              const float* __restrict__ bs,
                                              unsigned* __restrict__ nidx) {
  const int lane = threadIdx.x & 63;
  const int wid  = threadIdx.x >> 6;
  const int draw = (int)blockIdx.x * 4 + wid;   // 57344 draws
  const int row  = draw / KM1;

  // ---- stage 1: scan the row's 512 block sums (8 per lane)
  const float* bsr = bs + (size_t)row * NBLK;
  float4 v0 = *reinterpret_cast<const float4*>(bsr + lane * 8);
  float4 v1 = *reinterpret_cast<const float4*>(bsr + lane * 8 + 4);
  float s8 = ((v0.x + v0.y) + (v0.z + v0.w)) + ((v1.x + v1.y) + (v1.z + v1.w));
  float pre = wave_incl_scan(s8, lane);
  float W = __shfl(pre, 63);

  unsigned h = mix32((unsigned)draw * 2654435761u + 0x12345u);
  float u = ((float)(h >> 9) + 0.5f) * (1.0f / 8388608.0f);   // (0,1)

  if (!(W > 0.f)) {  // degenerate row -> uniform over all n
    if (lane == 0) nidx[draw] = mix32((unsigned)draw * 0x68bc21ebu + 77u) & (NN - 1);
    return;
  }
  float target = u * W;

  unsigned long long ball = __ballot(pre >= target);
  int Lc = ball ? ((int)__ffsll(ball) - 1) : 63;
  float exL = __shfl(pre - s8, Lc);
  float a0 = __shfl(v0.x, Lc), a1 = __shfl(v0.y, Lc), a2 = __shfl(v0.z, Lc),
        a3 = __shfl(v0.w, Lc), a4 = __shfl(v1.x, Lc), a5 = __shfl(v1.y, Lc),
        a6 = __shfl(v1.z, Lc), a7 = __shfl(v1.w, Lc);
  // uniform scalar selection among the 8 (static indexing only)
  int k = -1; float res = 0.f, bsb = 0.f, c = exL;
#define PICK(j, aj) { float cn = c + (aj); if (k < 0 && cn >= target) { k = j; res = target - c; bsb = (aj); } c = cn; }
  PICK(0, a0) PICK(1, a1) PICK(2, a2) PICK(3, a3)
  PICK(4, a4) PICK(5, a5) PICK(6, a6) PICK(7, a7)
#undef PICK
#define LASTP(j, aj) { if (k < 0 && (aj) > 0.f) { k = j; res = (aj); bsb = (aj); } }
  LASTP(7, a7) LASTP(6, a6) LASTP(5, a5) LASTP(4, a4)
  LASTP(3, a3) LASTP(2, a2) LASTP(1, a1) LASTP(0, a0)
#undef LASTP
  if (k < 0) {  // pathological: chosen lane empty -> uniform fallback
    if (lane == 0) nidx[draw] = mix32((unsigned)draw * 0x68bc21ebu + 77u) & (NN - 1);
    return;
  }
  const int blk = Lc * 8 + k;
  const int cb  = blk * 16;

  // ---- stage 2: recompute the 16 weights in fp32 (4 lanes/col x 32 dims)
  const int c_local = lane >> 2;
  const int part    = lane & 3;
  const int col     = cb + c_local;
  const unsigned short* cp = xb + (size_t)col * DD + part * 32;
  const unsigned short* ap = xb + (size_t)row * DD + part * 32;
  float dot = 0.f;
#pragma unroll
  for (int vv = 0; vv < 4; ++vv) {
    bf16x8 cv = *reinterpret_cast<const bf16x8*>(cp + vv * 8);
    bf16x8 av = *reinterpret_cast<const bf16x8*>(ap + vv * 8);
#pragma unroll
    for (int j = 0; j < 8; ++j) {
      float cf = __uint_as_float(((unsigned)(unsigned short)cv[j]) << 16);
      float af = __uint_as_float(((unsigned)(unsigned short)av[j]) << 16);
      dot = fmaf(cf, af, dot);
    }
  }
  dot += __shfl_xor(dot, 1);
  dot += __shfl_xor(dot, 2);
  float w = wfun(dot, col, row >> 3);
  float v = (part == 0) ? w : 0.f;
  float pre2 = wave_incl_scan(v, lane);
  float SW = __shfl(pre2, 63);
  unsigned result;
  if (SW > 0.f) {
    float t2 = (res / bsb) * SW;                 // renormalized residual
    unsigned long long m = __ballot((v > 0.f) && (pre2 >= t2));
    if (m) result = (unsigned)(cb + (((int)__ffsll(m) - 1) >> 2));
    else {
      unsigned long long m2 = __ballot(v > 0.f); // rounding overrun -> clamp
      result = (unsigned)(cb + ((63 - (int)__clzll(m2)) >> 2));
    }
  } else {
    result = mix32((unsigned)draw * 0x68bc21ebu + 77u) & (NN - 1);
  }
  if (lane == 0) nidx[draw] = result;
}

// All five output chunks, float4-vectorized.
__global__ __launch_bounds__(256) void write_outputs(const float* __restrict__ x,
                                                     const unsigned* __restrict__ nidx,
                                                     float4* __restrict__ out4) {
  const int qq = blockIdx.x * 256 + threadIdx.x;
  if (qq >= TOTAL / 4) return;
  const int e = qq * 4;
  float4 v;
  if (e < O0_END) {
    v.x = (float)((e    ) / KM1);
    v.y = (float)((e + 1) / KM1);
    v.z = (float)((e + 2) / KM1);
    v.w = (float)((e + 3) / KM1);                        // a_idx
  } else if (e < O1_END) {
    int t = e - O0_END; int sidx = t >> 7; int d = t & 127;
    v = *reinterpret_cast<const float4*>(x + (size_t)(sidx / KM1) * DD + d);   // x[a_idx]
  } else if (e < O2_END) {
    int t = e - O1_END; int sidx = t >> 7; int d = t & 127;
    int i = sidx / KM1; int j = sidx - i * KM1; int m = i & 7;
    int p = (i >> 3) * 8 + j + (j >= m ? 1 : 0);         // block members, skip self
    v = *reinterpret_cast<const float4*>(x + (size_t)p * DD + d);              // x[p_idx]
  } else if (e < O3_END) {
    int t = e - O2_END; int sidx = t >> 7; int d = t & 127;
    int nix = (int)nidx[sidx];
    v = *reinterpret_cast<const float4*>(x + (size_t)nix * DD + d);            // x[n_idx]
  } else {
    v = *reinterpret_cast<const float4*>(x + (e - O3_END));                    // x
  }
  out4[qq] = v;
}

extern "C" void kernel_launch(void* const* d_in, const int* in_sizes, int n_in,
                              void* d_out, int out_size, void* d_ws, size_t ws_size,
                              hipStream_t stream) {
  const float* x = (const float*)d_in[0];
  float* out = (float*)d_out;

  float* bs = (float*)d_ws;                                           // 8192*512 f32 = 16MB
  unsigned* nidx = (unsigned*)((char*)d_ws + (size_t)NN * NBLK * 4);  // 57344 u32
  unsigned short* xb = (unsigned short*)((char*)nidx + NKEY * 4);     // 2MB bf16

  hipLaunchKernelGGL(to_bf16, dim3(NN * DD / 4 / 256), dim3(256), 0, stream,
                     (const float4*)x, (ushort4*)xb);
  hipLaunchKernelGGL(pass_a, dim3(512), dim3(TPB), 0, stream, xb, bs);
  hipLaunchKernelGGL(pass_b, dim3(NKEY / 4), dim3(TPB), 0, stream, xb, bs, nidx);
  hipLaunchKernelGGL(write_outputs, dim3(TOTAL / 4 / 256), dim3(256), 0, stream,
                     x, nidx, (float4*)out);
}

// Round 17
// 113.093 us; speedup vs baseline: 1.1825x; 1.0317x over previous
//
#include <hip/hip_runtime.h>

#define NN   8192
#define DD   128
#define KM1  7
#define TPB  256
#define NBLK 512      // 16-col weight blocks per row

#define O0_END   57344
#define O1_END   7397376
#define O2_END   14737408
#define O3_END   22077440
#define TOTAL    23126016
#define NKEY     57344

typedef __attribute__((ext_vector_type(8))) short bf16x8;
typedef __attribute__((ext_vector_type(4))) float f32x4;

__device__ __forceinline__ unsigned mix32(unsigned h) {
  h ^= h >> 16; h *= 0x85ebca6bu; h ^= h >> 13; h *= 0xc2b2ae35u; h ^= h >> 16;
  return h;
}

// Weight of pair given dot (bf16 inputs). Same formula in both passes.
__device__ __forceinline__ float wfun(float dot, int col, int rowblk) {
  float d2m = fmaxf(fmaf(-2.f, dot, 2.f), 0.25f);      // clamped dist^2
  bool vb = ((col >> 3) != rowblk) && (d2m < 1.96f);   // block mask + dist<1.4
  float lgd = __log2f(d2m);
  float om  = fmaf(-0.25f, d2m, 1.f);
  float lgo = __log2f(om);
  float lgw = fmaf(-62.5f, lgo, fmaf(-63.f, lgd, -63.f));  // log2 w
  float w   = __builtin_amdgcn_exp2f(lgw);             // w in [8e-20, 5e20]
  return vb ? w : 0.f;
}

__device__ __forceinline__ float wave_incl_scan(float v, int lane) {
#pragma unroll
  for (int off = 1; off < 64; off <<= 1) {
    float t = __shfl_up(v, off);
    if (lane >= off) v += t;
  }
  return v;
}

// fp32 -> bf16 (RNE), 4 elems/thread
__global__ __launch_bounds__(256) void to_bf16(const float4* __restrict__ x4,
                                               ushort4* __restrict__ xb4) {
  const int i = blockIdx.x * 256 + threadIdx.x;
  float4 v = x4[i];
  ushort4 o;
  unsigned u;
  u = __float_as_uint(v.x); o.x = (unsigned short)((u + 0x7FFFu + ((u >> 16) & 1u)) >> 16);
  u = __float_as_uint(v.y); o.y = (unsigned short)((u + 0x7FFFu + ((u >> 16) & 1u)) >> 16);
  u = __float_as_uint(v.z); o.z = (unsigned short)((u + 0x7FFFu + ((u >> 16) & 1u)) >> 16);
  u = __float_as_uint(v.w); o.w = (unsigned short)((u + 0x7FFFu + ((u >> 16) & 1u)) >> 16);
  xb4[i] = o;
}

// Pass A (swapped operands, 64 rows/wave): wave = 64 rows x 256 cols (8 tiles).
// grid = 32 row-groups x 32 col-chunks = 1024 blocks -> 4 waves/SIMD resident.
// Stores: each lane owns row i0+lane and writes its 16 block sums as one
// contiguous 64 B chunk (full cache line, no RMW amplification).
__global__ __launch_bounds__(TPB, 2) void pass_a(const unsigned short* __restrict__ xb,
                                                 float* __restrict__ bs) {
  const int tid  = threadIdx.x;
  const int lane = tid & 63;
  const int wid  = tid >> 6;
  const int l15  = lane & 15;
  const int g    = lane >> 4;
  const int i0   = ((int)(blockIdx.x >> 5)) * 256 + wid * 64;  // wave's 64 rows
  const int oc   = (int)(blockIdx.x & 31);
  const int c0   = oc * 256;
  const int koff = g * 8;

  // row fragments (B operand, n = row): 4 groups of 16 rows, loaded once
  bf16x8 rw[4][4];
#pragma unroll
  for (int rg = 0; rg < 4; ++rg) {
    const unsigned short* rp = xb + (size_t)(i0 + rg * 16 + l15) * DD + koff;
#pragma unroll
    for (int kk = 0; kk < 4; ++kk)
      rw[rg][kk] = *reinterpret_cast<const bf16x8*>(rp + kk * 32);
  }

  float bsl[16];     // this lane's row (i0+lane): 16 block sums, static-indexed
#pragma unroll
  for (int j = 0; j < 16; ++j) bsl[j] = 0.f;

#pragma unroll 1
  for (int t = 0; t < 8; ++t) {           // 32-col tiles = 2 x 16-col blocks
    const int ct = c0 + t * 32;
    // col fragments (A operand, m = col): lane l15 -> col ct+mf*16+l15
    bf16x8 cf[2][4];
#pragma unroll
    for (int mf = 0; mf < 2; ++mf) {
      const unsigned short* cp = xb + (size_t)(ct + mf * 16 + l15) * DD + koff;
#pragma unroll
      for (int kk = 0; kk < 4; ++kk)
        cf[mf][kk] = *reinterpret_cast<const bf16x8*>(cp + kk * 32);
    }

    f32x4 acc[2][4];
#pragma unroll
    for (int mf = 0; mf < 2; ++mf)
#pragma unroll
      for (int rg = 0; rg < 4; ++rg) acc[mf][rg] = (f32x4){0.f, 0.f, 0.f, 0.f};

#pragma unroll
    for (int mf = 0; mf < 2; ++mf)
#pragma unroll
      for (int rg = 0; rg < 4; ++rg)
#pragma unroll
        for (int kk = 0; kk < 4; ++kk)
          acc[mf][rg] = __builtin_amdgcn_mfma_f32_16x16x32_bf16(cf[mf][kk], rw[rg][kk],
                                                                acc[mf][rg], 0, 0, 0);

    // D layout [m89]: n = l15 -> ROW (group rg); m = g*4+reg -> COL
#pragma unroll
    for (int mf = 0; mf < 2; ++mf) {
      float s[4];
#pragma unroll
      for (int rg = 0; rg < 4; ++rg) {
        const int rowblk = (i0 + rg * 16 + l15) >> 3;
        float sv = 0.f;
#pragma unroll
        for (int r = 0; r < 4; ++r) {
          const int col = ct + mf * 16 + g * 4 + r;
          sv += wfun(acc[mf][rg][r], col, rowblk);
        }
        sv += __shfl_xor(sv, 16);
        sv += __shfl_xor(sv, 32);          // sum over g -> 16-col block sum
        s[rg] = sv;
      }
      // keep the rg == g slice: lane now owns row i0+lane
      float v = (g == 0) ? s[0] : (g == 1) ? s[1] : (g == 2) ? s[2] : s[3];
      bsl[2 * t + mf] = v;
    }
  }

  // coalesced write: lane's row chunk = 16 consecutive floats (one 64 B line)
  float* dst = bs + (size_t)(i0 + lane) * NBLK + oc * 16;
#pragma unroll
  for (int k4 = 0; k4 < 4; ++k4) {
    f32x4 o = {bsl[4 * k4], bsl[4 * k4 + 1], bsl[4 * k4 + 2], bsl[4 * k4 + 3]};
    *reinterpret_cast<f32x4*>(dst + 4 * k4) = o;
  }
}

// Pass B: one wave per draw. Two-level inverse-CDF: 512 block sums -> 16-col
// block -> fp32 recompute of the 16 weights (4 lanes/col x 32 dims).
__global__ __launch_bounds__(TPB) void pass_b(const unsigned short* __restrict__ xb,
                                              const float* __restrict__ bs,
                                              unsigned* __restrict__ nidx) {
  const int lane = threadIdx.x & 63;
  const int wid  = threadIdx.x >> 6;
  const int draw = (int)blockIdx.x * 4 + wid;   // 57344 draws
  const int row  = draw / KM1;

  // ---- stage 1: scan the row's 512 block sums (8 per lane)
  const float* bsr = bs + (size_t)row * NBLK;
  float4 v0 = *reinterpret_cast<const float4*>(bsr + lane * 8);
  float4 v1 = *reinterpret_cast<const float4*>(bsr + lane * 8 + 4);
  float s8 = ((v0.x + v0.y) + (v0.z + v0.w)) + ((v1.x + v1.y) + (v1.z + v1.w));
  float pre = wave_incl_scan(s8, lane);
  float W = __shfl(pre, 63);

  unsigned h = mix32((unsigned)draw * 2654435761u + 0x12345u);
  float u = ((float)(h >> 9) + 0.5f) * (1.0f / 8388608.0f);   // (0,1)

  if (!(W > 0.f)) {  // degenerate row -> uniform over all n
    if (lane == 0) nidx[draw] = mix32((unsigned)draw * 0x68bc21ebu + 77u) & (NN - 1);
    return;
  }
  float target = u * W;

  unsigned long long ball = __ballot(pre >= target);
  int Lc = ball ? ((int)__ffsll(ball) - 1) : 63;
  float exL = __shfl(pre - s8, Lc);
  float a0 = __shfl(v0.x, Lc), a1 = __shfl(v0.y, Lc), a2 = __shfl(v0.z, Lc),
        a3 = __shfl(v0.w, Lc), a4 = __shfl(v1.x, Lc), a5 = __shfl(v1.y, Lc),
        a6 = __shfl(v1.z, Lc), a7 = __shfl(v1.w, Lc);
  // uniform scalar selection among the 8 (static indexing only)
  int k = -1; float res = 0.f, bsb = 0.f, c = exL;
#define PICK(j, aj) { float cn = c + (aj); if (k < 0 && cn >= target) { k = j; res = target - c; bsb = (aj); } c = cn; }
  PICK(0, a0) PICK(1, a1) PICK(2, a2) PICK(3, a3)
  PICK(4, a4) PICK(5, a5) PICK(6, a6) PICK(7, a7)
#undef PICK
#define LASTP(j, aj) { if (k < 0 && (aj) > 0.f) { k = j; res = (aj); bsb = (aj); } }
  LASTP(7, a7) LASTP(6, a6) LASTP(5, a5) LASTP(4, a4)
  LASTP(3, a3) LASTP(2, a2) LASTP(1, a1) LASTP(0, a0)
#undef LASTP
  if (k < 0) {  // pathological: chosen lane empty -> uniform fallback
    if (lane == 0) nidx[draw] = mix32((unsigned)draw * 0x68bc21ebu + 77u) & (NN - 1);
    return;
  }
  const int blk = Lc * 8 + k;
  const int cb  = blk * 16;

  // ---- stage 2: recompute the 16 weights in fp32 (4 lanes/col x 32 dims)
  const int c_local = lane >> 2;
  const int part    = lane & 3;
  const int col     = cb + c_local;
  const unsigned short* cp = xb + (size_t)col * DD + part * 32;
  const unsigned short* ap = xb + (size_t)row * DD + part * 32;
  float dot = 0.f;
#pragma unroll
  for (int vv = 0; vv < 4; ++vv) {
    bf16x8 cv = *reinterpret_cast<const bf16x8*>(cp + vv * 8);
    bf16x8 av = *reinterpret_cast<const bf16x8*>(ap + vv * 8);
#pragma unroll
    for (int j = 0; j < 8; ++j) {
      float cf = __uint_as_float(((unsigned)(unsigned short)cv[j]) << 16);
      float af = __uint_as_float(((unsigned)(unsigned short)av[j]) << 16);
      dot = fmaf(cf, af, dot);
    }
  }
  dot += __shfl_xor(dot, 1);
  dot += __shfl_xor(dot, 2);
  float w = wfun(dot, col, row >> 3);
  float v = (part == 0) ? w : 0.f;
  float pre2 = wave_incl_scan(v, lane);
  float SW = __shfl(pre2, 63);
  unsigned result;
  if (SW > 0.f) {
    float t2 = (res / bsb) * SW;                 // renormalized residual
    unsigned long long m = __ballot((v > 0.f) && (pre2 >= t2));
    if (m) result = (unsigned)(cb + (((int)__ffsll(m) - 1) >> 2));
    else {
      unsigned long long m2 = __ballot(v > 0.f); // rounding overrun -> clamp
      result = (unsigned)(cb + ((63 - (int)__clzll(m2)) >> 2));
    }
  } else {
    result = mix32((unsigned)draw * 0x68bc21ebu + 77u) & (NN - 1);
  }
  if (lane == 0) nidx[draw] = result;
}

// All five output chunks, float4-vectorized, nontemporal stores.
__global__ __launch_bounds__(256) void write_outputs(const float* __restrict__ x,
                                                     const unsigned* __restrict__ nidx,
                                                     float* __restrict__ out) {
  const int qq = blockIdx.x * 256 + threadIdx.x;
  if (qq >= TOTAL / 4) return;
  const int e = qq * 4;
  float4 v;
  if (e < O0_END) {
    v.x = (float)((e    ) / KM1);
    v.y = (float)((e + 1) / KM1);
    v.z = (float)((e + 2) / KM1);
    v.w = (float)((e + 3) / KM1);                        // a_idx
  } else if (e < O1_END) {
    int t = e - O0_END; int sidx = t >> 7; int d = t & 127;
    v = *reinterpret_cast<const float4*>(x + (size_t)(sidx / KM1) * DD + d);   // x[a_idx]
  } else if (e < O2_END) {
    int t = e - O1_END; int sidx = t >> 7; int d = t & 127;
    int i = sidx / KM1; int j = sidx - i * KM1; int m = i & 7;
    int p = (i >> 3) * 8 + j + (j >= m ? 1 : 0);         // block members, skip self
    v = *reinterpret_cast<const float4*>(x + (size_t)p * DD + d);              // x[p_idx]
  } else if (e < O3_END) {
    int t = e - O2_END; int sidx = t >> 7; int d = t & 127;
    int nix = (int)nidx[sidx];
    v = *reinterpret_cast<const float4*>(x + (size_t)nix * DD + d);            // x[n_idx]
  } else {
    v = *reinterpret_cast<const float4*>(x + (e - O3_END));                    // x
  }
  f32x4 nv = {v.x, v.y, v.z, v.w};
  __builtin_nontemporal_store(nv, reinterpret_cast<f32x4*>(out + e));
}

extern "C" void kernel_launch(void* const* d_in, const int* in_sizes, int n_in,
                              void* d_out, int out_size, void* d_ws, size_t ws_size,
                              hipStream_t stream) {
  const float* x = (const float*)d_in[0];
  float* out = (float*)d_out;

  float* bs = (float*)d_ws;                                           // 8192*512 f32 = 16MB
  unsigned* nidx = (unsigned*)((char*)d_ws + (size_t)NN * NBLK * 4);  // 57344 u32
  unsigned short* xb = (unsigned short*)((char*)nidx + NKEY * 4);     // 2MB bf16

  hipLaunchKernelGGL(to_bf16, dim3(NN * DD / 4 / 256), dim3(256), 0, stream,
                     (const float4*)x, (ushort4*)xb);
  hipLaunchKernelGGL(pass_a, dim3(1024), dim3(TPB), 0, stream, xb, bs);
  hipLaunchKernelGGL(pass_b, dim3(NKEY / 4), dim3(TPB), 0, stream, xb, bs, nidx);
  hipLaunchKernelGGL(write_outputs, dim3(TOTAL / 4 / 256), dim3(256), 0, stream,
                     x, nidx, out);
}